// Round 2
// baseline (445.921 us; speedup 1.0000x reference)
//
#include <hip/hip_runtime.h>
#include <hip/hip_bf16.h>
#include <math.h>

// Reverse cummax along axis 1 of [B=16, H=128, W=128, C=256] fp32.
// out[b,h,w,c] = max_{h'>=h} in[b,h',w,c].
// One thread per (b, w, c/4) column. Software-pipelined tiles of T=8 float4s:
// prefetch tile t-1 while computing/storing tile t -> 8 loads in flight/wave.

#define B 16
#define H 128
#define W 128
#define C4 64        // C/4
#define T 8          // float4s per tile
#define NT (H / T)   // 16 tiles per column

__device__ inline float4 fmax4(float4 a, float4 b) {
    return make_float4(fmaxf(a.x, b.x), fmaxf(a.y, b.y),
                       fmaxf(a.z, b.z), fmaxf(a.w, b.w));
}

__global__ void __launch_bounds__(256) rev_cummax_kernel(
    const float4* __restrict__ in, float4* __restrict__ out) {
    int tid = blockIdx.x * blockDim.x + threadIdx.x;  // 0 .. B*W*C4-1
    int c4 = tid & (C4 - 1);
    int w  = (tid >> 6) & (W - 1);
    int b  = tid >> 13;

    const int hstride = W * C4;                      // 8192 float4s per h step
    const int base = (b * H * W + w) * C4 + c4;      // offset of h=0

    float4 cur[T], nxt[T], res[T];

    // Prologue: load the top tile (t = NT-1, h = 120..127).
    {
        const int h0 = (NT - 1) * T;
#pragma unroll
        for (int j = 0; j < T; ++j)
            cur[j] = in[base + (h0 + j) * hstride];
    }

    float4 m = make_float4(-INFINITY, -INFINITY, -INFINITY, -INFINITY);

    for (int t = NT - 1; t >= 0; --t) {
        // Prefetch next (lower-h) tile while we compute on cur.
        if (t > 0) {
            const int h0 = (t - 1) * T;
#pragma unroll
            for (int j = 0; j < T; ++j)
                nxt[j] = in[base + (h0 + j) * hstride];
        }
        // Suffix max within the tile, chaining the running max m from above.
#pragma unroll
        for (int j = T - 1; j >= 0; --j) {
            m = fmax4(m, cur[j]);
            res[j] = m;
        }
        // Store the tile.
        {
            const int h0 = t * T;
#pragma unroll
            for (int j = 0; j < T; ++j)
                out[base + (h0 + j) * hstride] = res[j];
        }
        // Rotate buffers.
#pragma unroll
        for (int j = 0; j < T; ++j) cur[j] = nxt[j];
    }
}

extern "C" void kernel_launch(void* const* d_in, const int* in_sizes, int n_in,
                              void* d_out, int out_size, void* d_ws, size_t ws_size,
                              hipStream_t stream) {
    const float4* in = (const float4*)d_in[0];
    float4* out = (float4*)d_out;
    const int nthreads = B * W * C4;  // 131072
    rev_cummax_kernel<<<nthreads / 256, 256, 0, stream>>>(in, out);
}